// Round 1
// baseline (258.516 us; speedup 1.0000x reference)
//
#include <hip/hip_runtime.h>
#include <hip/hip_bf16.h>

#define NN 8192
#define FIN 512
#define FOUT 256
#define JSPLIT 4
#define JCHUNK (NN / JSPLIT)  // 2048

typedef float f32x4 __attribute__((ext_vector_type(4)));
typedef short bf16x8 __attribute__((ext_vector_type(8)));
typedef unsigned short us8 __attribute__((ext_vector_type(8)));

static __device__ __forceinline__ unsigned short f2bf(float x) {
  unsigned int u = __builtin_bit_cast(unsigned int, x);
  unsigned int r = (u + 0x7fffu + ((u >> 16) & 1u)) >> 16;  // RNE
  return (unsigned short)r;
}
static __device__ __forceinline__ float bf2f(unsigned short u) {
  unsigned int v = ((unsigned int)u) << 16;
  return __builtin_bit_cast(float, v);
}

// ---------------- Phase A: Wh = x @ W  (fp32, 64x64 tile) ----------------
__global__ __launch_bounds__(256) void gemm_xw(const float* __restrict__ X,
                                               const float* __restrict__ W,
                                               float* __restrict__ Wh) {
  __shared__ float As[16][68];
  __shared__ float Bs[16][68];
  const int tid = threadIdx.x;
  const int tx = tid & 15, ty = tid >> 4;
  const int m0 = blockIdx.y * 64, n0 = blockIdx.x * 64;
  const int ka = tid & 15, ma = tid >> 4;
  const int nb_ = tid & 63, kb_ = tid >> 6;
  float acc[4][4] = {};
  for (int K0 = 0; K0 < FIN; K0 += 16) {
#pragma unroll
    for (int i = 0; i < 4; ++i)
      As[ka][ma + 16 * i] = X[(size_t)(m0 + ma + 16 * i) * FIN + K0 + ka];
#pragma unroll
    for (int i = 0; i < 4; ++i)
      Bs[kb_ + 4 * i][nb_] = W[(size_t)(K0 + kb_ + 4 * i) * FOUT + n0 + nb_];
    __syncthreads();
#pragma unroll
    for (int k = 0; k < 16; ++k) {
      const float4 av = *(const float4*)&As[k][ty * 4];
      const float4 bv = *(const float4*)&Bs[k][tx * 4];
      const float a4[4] = {av.x, av.y, av.z, av.w};
      const float b4[4] = {bv.x, bv.y, bv.z, bv.w};
#pragma unroll
      for (int i = 0; i < 4; ++i)
#pragma unroll
        for (int j = 0; j < 4; ++j) acc[i][j] += a4[i] * b4[j];
    }
    __syncthreads();
  }
#pragma unroll
  for (int i = 0; i < 4; ++i) {
    float4 v = make_float4(acc[i][0], acc[i][1], acc[i][2], acc[i][3]);
    *(float4*)&Wh[(size_t)(m0 + ty * 4 + i) * FOUT + n0 + tx * 4] = v;
  }
}

// ------------- Phase A2: s_src[i] = Wh[i,:].a_src ; s_dst likewise -------------
__global__ __launch_bounds__(256) void compute_s(const float* __restrict__ Wh,
                                                 const float* __restrict__ a,
                                                 float* __restrict__ ssrc,
                                                 float* __restrict__ sdst) {
  const int wave = threadIdx.x >> 6, lane = threadIdx.x & 63;
  const int row = blockIdx.x * 4 + wave;
  const float4 w = ((const float4*)(Wh + (size_t)row * FOUT))[lane];
  const float4 as = ((const float4*)a)[lane];
  const float4 ad = ((const float4*)(a + FOUT))[lane];
  float vs = w.x * as.x + w.y * as.y + w.z * as.z + w.w * as.w;
  float vd = w.x * ad.x + w.y * ad.y + w.z * ad.z + w.w * ad.w;
#pragma unroll
  for (int off = 32; off; off >>= 1) {
    vs += __shfl_xor(vs, off);
    vd += __shfl_xor(vd, off);
  }
  if (lane == 0) { ssrc[row] = vs; sdst[row] = vd; }
}

// ------------- Phase A3: Wh -> split bf16 hi/lo in MFMA-B layout -------------
// WhB[jblk][n][jin] = Wh[jblk*8 + jin][n], jblk<1024, n<256, jin<8
__global__ __launch_bounds__(256) void build_whb(const float* __restrict__ Wh,
                                                 unsigned short* __restrict__ Bh,
                                                 unsigned short* __restrict__ Bl) {
  const int idx = blockIdx.x * 256 + threadIdx.x;  // < 262144
  const int jblk = idx >> 8, n = idx & 255;
  us8 vh, vl;
#pragma unroll
  for (int e = 0; e < 8; ++e) {
    float v = Wh[(size_t)(jblk * 8 + e) * FOUT + n];
    unsigned short hi = f2bf(v);
    vh[e] = hi;
    vl[e] = f2bf(v - bf2f(hi));
  }
  *(us8*)(Bh + (size_t)idx * 8) = vh;
  *(us8*)(Bl + (size_t)idx * 8) = vl;
}

// ------------- Phase B: fused attention aggregation (one pass, no max) -------------
// grid (64, JSPLIT), block 512 (8 waves). Wave w owns rows bm*128+w*16 .. +15,
// iterates the block's j-chunk; p-tile generated in A-frag layout; U += p*(Whh+Whl).
__global__ __launch_bounds__(512, 2) void gat_aggr(
    const int* __restrict__ adj, const float* __restrict__ ssrc_g,
    const float* __restrict__ sdst_g, const unsigned short* __restrict__ Bh,
    const unsigned short* __restrict__ Bl, float* __restrict__ Up,
    float* __restrict__ Dp) {
  const int bm = blockIdx.x;  // 0..63
  const int bj = blockIdx.y;  // 0..JSPLIT-1
  const int wave = threadIdx.x >> 6;
  const int lane = threadIdx.x & 63;
  const int r = lane & 15, kb = lane >> 4;
  const int row16 = bm * 128 + wave * 16;
  const int myrow = row16 + r;
  const float ssrc = ssrc_g[myrow];
  const size_t adjbase = (size_t)myrow * NN;
  const int jb = bj * JCHUNK;

  f32x4 acc[16];
#pragma unroll
  for (int i = 0; i < 16; ++i) acc[i] = (f32x4){0.f, 0.f, 0.f, 0.f};
  float dacc = 0.f;

  // prefetch first adj / s_dst chunk
  int4 a0 = ((const int4*)(adj + adjbase + jb + kb * 8))[0];
  int4 a1 = ((const int4*)(adj + adjbase + jb + kb * 8))[1];
  float4 s0 = ((const float4*)(sdst_g + jb + kb * 8))[0];
  float4 s1 = ((const float4*)(sdst_g + jb + kb * 8))[1];

  for (int step = 0; step < JCHUNK / 32; ++step) {
    const int j0 = jb + step * 32;
    bf16x8 af;
    {
      float t, pe;
      unsigned short hb;
#define GEN(E, AV, SV)                                   \
      t = ssrc + (SV);                                   \
      t = t > 0.f ? t : 0.2f * t;                        \
      pe = (AV) != 0 ? __expf(t) : 1.0f;                 \
      hb = f2bf(pe);                                     \
      af[E] = (short)hb;                                 \
      dacc += bf2f(hb);
      GEN(0, a0.x, s0.x) GEN(1, a0.y, s0.y) GEN(2, a0.z, s0.z) GEN(3, a0.w, s0.w)
      GEN(4, a1.x, s1.x) GEN(5, a1.y, s1.y) GEN(6, a1.z, s1.z) GEN(7, a1.w, s1.w)
#undef GEN
    }
    // prefetch next chunk while MFMAs run
    if (step + 1 < JCHUNK / 32) {
      const int jn = jb + (step + 1) * 32 + kb * 8;
      a0 = ((const int4*)(adj + adjbase + jn))[0];
      a1 = ((const int4*)(adj + adjbase + jn))[1];
      s0 = ((const float4*)(sdst_g + jn))[0];
      s1 = ((const float4*)(sdst_g + jn))[1];
    }
    const size_t bbase = ((size_t)(j0 >> 3) + kb) * (FOUT * 8) + (size_t)r * 8;
#pragma unroll
    for (int nb = 0; nb < 16; ++nb) {
      bf16x8 vh = *(const bf16x8*)(Bh + bbase + nb * 128);
      bf16x8 vl = *(const bf16x8*)(Bl + bbase + nb * 128);
      acc[nb] = __builtin_amdgcn_mfma_f32_16x16x32_bf16(af, vh, acc[nb], 0, 0, 0);
      acc[nb] = __builtin_amdgcn_mfma_f32_16x16x32_bf16(af, vl, acc[nb], 0, 0, 0);
    }
  }

  // D: reduce over kb groups (lanes r, r+16, r+32, r+48 share a row)
  dacc += __shfl_xor(dacc, 16);
  dacc += __shfl_xor(dacc, 32);
  if (kb == 0) Dp[(size_t)bj * NN + myrow] = dacc;

  // U: D-frag layout col = r, row = kb*4+q
  float* ub = Up + ((size_t)bj * NN + row16) * FOUT;
#pragma unroll
  for (int nb = 0; nb < 16; ++nb)
#pragma unroll
    for (int q = 0; q < 4; ++q)
      ub[(size_t)(kb * 4 + q) * FOUT + nb * 16 + r] = acc[nb][q];
}

// ------------- Phase C: combine j-splits, divide, head-mean -------------
__global__ __launch_bounds__(256) void finalize(const float* __restrict__ Up,
                                                const float* __restrict__ Dp,
                                                float* __restrict__ out) {
  const int idx = blockIdx.x * 256 + threadIdx.x;  // < 8192*64
  const int i = idx >> 6, c = idx & 63;
  float u = 0.f, d = 0.f;
#pragma unroll
  for (int s = 0; s < JSPLIT; ++s) {
    d += Dp[(size_t)s * NN + i];
    const float* up = Up + ((size_t)s * NN + i) * FOUT + c;
#pragma unroll
    for (int g = 0; g < 4; ++g) u += up[g * 64];
  }
  out[idx] = u / (4.f * d);
}

extern "C" void kernel_launch(void* const* d_in, const int* in_sizes, int n_in,
                              void* d_out, int out_size, void* d_ws, size_t ws_size,
                              hipStream_t stream) {
  const float* x = (const float*)d_in[0];
  const int* adj = (const int*)d_in[1];
  const float* W = (const float*)d_in[2];
  const float* a = (const float*)d_in[3];
  char* ws = (char*)d_ws;

  float* Wh = (float*)ws;                                          // 8 MB
  unsigned short* Bh = (unsigned short*)(ws + (8u << 20));         // 4 MB
  unsigned short* Bl = (unsigned short*)(ws + (12u << 20));        // 4 MB
  float* ssrc = (float*)(ws + (16u << 20));                        // 32 KB
  float* sdst = (float*)(ws + (16u << 20) + (32u << 10));          // 32 KB
  float* Dp = (float*)(ws + (16u << 20) + (64u << 10));            // 128 KB
  float* Up = (float*)(ws + (17u << 20));                          // 32 MB
  float* out = (float*)d_out;

  gemm_xw<<<dim3(FOUT / 64, NN / 64), 256, 0, stream>>>(x, W, Wh);
  compute_s<<<NN / 4, 256, 0, stream>>>(Wh, a, ssrc, sdst);
  build_whb<<<(NN / 8) * FOUT / 256, 256, 0, stream>>>(Wh, Bh, Bl);
  gat_aggr<<<dim3(NN / 128, JSPLIT), 512, 0, stream>>>(adj, ssrc, sdst, Bh, Bl, Up, Dp);
  finalize<<<NN * 64 / 256, 256, 0, stream>>>(Up, Dp, out);
}

// Round 2
// 224.680 us; speedup vs baseline: 1.1506x; 1.1506x over previous
//
#include <hip/hip_runtime.h>
#include <hip/hip_bf16.h>

#define NN 8192
#define FIN 512
#define FOUT 256
#define JSPLIT 8
#define JCHUNK (NN / JSPLIT)  // 1024
#define STEPS (JCHUNK / 32)   // 32

typedef float f32x16 __attribute__((ext_vector_type(16)));
typedef short bf16x8 __attribute__((ext_vector_type(8)));
typedef unsigned short us8 __attribute__((ext_vector_type(8)));

static __device__ __forceinline__ unsigned short f2bf(float x) {
  unsigned int u = __builtin_bit_cast(unsigned int, x);
  unsigned int r = (u + 0x7fffu + ((u >> 16) & 1u)) >> 16;  // RNE
  return (unsigned short)r;
}
static __device__ __forceinline__ float bf2f(unsigned short u) {
  unsigned int v = ((unsigned int)u) << 16;
  return __builtin_bit_cast(float, v);
}
static __device__ __forceinline__ float fastexp2(float x) {
  float r;
  asm("v_exp_f32 %0, %1" : "=v"(r) : "v"(x));
  return r;
}

// ---------------- Phase A: Wh = x @ W  (fp32, 64x64 tile) ----------------
__global__ __launch_bounds__(256) void gemm_xw(const float* __restrict__ X,
                                               const float* __restrict__ W,
                                               float* __restrict__ Wh) {
  __shared__ float As[16][68];
  __shared__ float Bs[16][68];
  const int tid = threadIdx.x;
  const int tx = tid & 15, ty = tid >> 4;
  const int m0 = blockIdx.y * 64, n0 = blockIdx.x * 64;
  const int ka = tid & 15, ma = tid >> 4;
  const int nb_ = tid & 63, kb_ = tid >> 6;
  float acc[4][4] = {};
  for (int K0 = 0; K0 < FIN; K0 += 16) {
#pragma unroll
    for (int i = 0; i < 4; ++i)
      As[ka][ma + 16 * i] = X[(size_t)(m0 + ma + 16 * i) * FIN + K0 + ka];
#pragma unroll
    for (int i = 0; i < 4; ++i)
      Bs[kb_ + 4 * i][nb_] = W[(size_t)(K0 + kb_ + 4 * i) * FOUT + n0 + nb_];
    __syncthreads();
#pragma unroll
    for (int k = 0; k < 16; ++k) {
      const float4 av = *(const float4*)&As[k][ty * 4];
      const float4 bv = *(const float4*)&Bs[k][tx * 4];
      const float a4[4] = {av.x, av.y, av.z, av.w};
      const float b4[4] = {bv.x, bv.y, bv.z, bv.w};
#pragma unroll
      for (int i = 0; i < 4; ++i)
#pragma unroll
        for (int j = 0; j < 4; ++j) acc[i][j] += a4[i] * b4[j];
    }
    __syncthreads();
  }
#pragma unroll
  for (int i = 0; i < 4; ++i) {
    float4 v = make_float4(acc[i][0], acc[i][1], acc[i][2], acc[i][3]);
    *(float4*)&Wh[(size_t)(m0 + ty * 4 + i) * FOUT + n0 + tx * 4] = v;
  }
}

// ------- Phase A2: s_src/s_dst (PRE-SCALED by log2(e) for v_exp_f32) -------
__global__ __launch_bounds__(256) void compute_s(const float* __restrict__ Wh,
                                                 const float* __restrict__ a,
                                                 float* __restrict__ ssrc,
                                                 float* __restrict__ sdst) {
  const int wave = threadIdx.x >> 6, lane = threadIdx.x & 63;
  const int row = blockIdx.x * 4 + wave;
  const float4 w = ((const float4*)(Wh + (size_t)row * FOUT))[lane];
  const float4 as = ((const float4*)a)[lane];
  const float4 ad = ((const float4*)(a + FOUT))[lane];
  float vs = w.x * as.x + w.y * as.y + w.z * as.z + w.w * as.w;
  float vd = w.x * ad.x + w.y * ad.y + w.z * ad.z + w.w * ad.w;
#pragma unroll
  for (int off = 32; off; off >>= 1) {
    vs += __shfl_xor(vs, off);
    vd += __shfl_xor(vd, off);
  }
  if (lane == 0) {
    ssrc[row] = vs * 1.44269504f;
    sdst[row] = vd * 1.44269504f;
  }
}

// ------- Phase A3: Wh -> bf16 hi/lo in 32x32x16 MFMA-B fragment order -------
// Tile per jw (32 j): [h(2)][kc(2)][kh(2)][n(256)][e(8)] bf16 = 16384 shorts.
// B element (kc,kh,n,e) = Wh[jw*32 + kc*16 + kh*8 + e][n].
__global__ __launch_bounds__(256) void build_whb(const float* __restrict__ Wh,
                                                 unsigned short* __restrict__ Bg) {
  const int idx = blockIdx.x * 256 + threadIdx.x;  // < 1024*256
  const int jo = idx >> 8, n = idx & 255;          // jo = j>>3
  const int jw = jo >> 2, kc = (jo >> 1) & 1, kh = jo & 1;
  us8 vh, vl;
#pragma unroll
  for (int e = 0; e < 8; ++e) {
    float v = Wh[(size_t)(jo * 8 + e) * FOUT + n];
    unsigned short hi = f2bf(v);
    vh[e] = hi;
    vl[e] = f2bf(v - bf2f(hi));
  }
  const size_t base = (size_t)jw * 16384 + ((kc * 2 + kh) * 256 + n) * 8;
  *(us8*)(Bg + base) = vh;
  *(us8*)(Bg + base + 8192) = vl;  // h stride = 8192 shorts
}

// ------------- Phase B: fused attention aggregation, no-LDS, 32x32x16 -------------
// grid 256 (1/CU), block 512 (8 waves). bj = bid&7 (XCD-pinned j-split).
// Wave: rowgroup rg = wv>>1 (64 rows), n-half nh = wv&1 (128 cols).
__global__ __launch_bounds__(512, 2) void gat_aggr(
    const int* __restrict__ adj, const float* __restrict__ ssrc_g,
    const float* __restrict__ sdst_g, const unsigned short* __restrict__ Bg,
    unsigned short* __restrict__ Upb, float* __restrict__ Dp) {
  const int bid = blockIdx.x;
  const int bj = bid & 7;
  const int bm = bid >> 3;  // 0..31
  const int wv = threadIdx.x >> 6;
  const int lane = threadIdx.x & 63;
  const int l31 = lane & 31, kh = lane >> 5;
  const int rg = wv >> 1, nh = wv & 1;
  const int rbase = bm * 256 + rg * 64;
  const int jb = bj * JCHUNK;

  const float ss0 = ssrc_g[rbase + l31];
  const float ss1 = ssrc_g[rbase + 32 + l31];

  f32x16 acc[2][4];
#pragma unroll
  for (int i = 0; i < 2; ++i)
#pragma unroll
    for (int j = 0; j < 4; ++j) acc[i][j] = (f32x16)(0.f);
  float d0 = 0.f, d1 = 0.f;

  const int* arow0 = adj + (size_t)(rbase + l31) * NN + jb + kh * 8;
  const int* arow1 = arow0 + (size_t)32 * NN;
  const float* sdp = sdst_g + jb + kh * 8;

  int4 aj[2][2][2];
#define LOAD_ADJ(T)                                          \
  {                                                          \
    aj[0][0][0] = *(const int4*)(arow0 + (T) * 32);          \
    aj[0][0][1] = *(const int4*)(arow0 + (T) * 32 + 4);      \
    aj[0][1][0] = *(const int4*)(arow0 + (T) * 32 + 16);     \
    aj[0][1][1] = *(const int4*)(arow0 + (T) * 32 + 20);     \
    aj[1][0][0] = *(const int4*)(arow1 + (T) * 32);          \
    aj[1][0][1] = *(const int4*)(arow1 + (T) * 32 + 4);      \
    aj[1][1][0] = *(const int4*)(arow1 + (T) * 32 + 16);     \
    aj[1][1][1] = *(const int4*)(arow1 + (T) * 32 + 20);     \
  }

  LOAD_ADJ(0);

#pragma unroll 1
  for (int t = 0; t < STEPS; ++t) {
    // ---- A-gen: p tile in A-frag layout (consumes prefetched adj) ----
    bf16x8 af[2][2];
#pragma unroll
    for (int rf = 0; rf < 2; ++rf) {
      const float srow = rf ? ss1 : ss0;
      float dloc = 0.f;
#pragma unroll
      for (int kc = 0; kc < 2; ++kc) {
        const float4 sa = *(const float4*)(sdp + t * 32 + kc * 16);
        const float4 sb = *(const float4*)(sdp + t * 32 + kc * 16 + 4);
        const int4 qa = aj[rf][kc][0];
        const int4 qb = aj[rf][kc][1];
        bf16x8 v;
#define GEN(E, Q, SD)                          \
        {                                      \
          float tt = srow + (SD);              \
          float lr = fmaxf(tt, 0.2f * tt);     \
          float pe = (Q) ? fastexp2(lr) : 1.0f;\
          unsigned short hb = f2bf(pe);        \
          v[E] = (short)hb;                    \
          dloc += bf2f(hb);                    \
        }
        GEN(0, qa.x, sa.x) GEN(1, qa.y, sa.y) GEN(2, qa.z, sa.z) GEN(3, qa.w, sa.w)
        GEN(4, qb.x, sb.x) GEN(5, qb.y, sb.y) GEN(6, qb.z, sb.z) GEN(7, qb.w, sb.w)
#undef GEN
        af[rf][kc] = v;
      }
      if (rf == 0) d0 += dloc; else d1 += dloc;
    }
    // ---- prefetch adj for next step (in flight during MFMAs) ----
    if (t + 1 < STEPS) LOAD_ADJ(t + 1);

    // ---- B loads (coalesced 16B/lane from pre-swizzled Bg) + MFMA ----
    const unsigned short* tb = Bg + (size_t)(bj * 32 + t) * 16384;
    const int boff = kh * 2048 + (nh * 128 + l31) * 8;
#pragma unroll
    for (int kc = 0; kc < 2; ++kc)
#pragma unroll
      for (int h = 0; h < 2; ++h)
#pragma unroll
        for (int nbi = 0; nbi < 4; ++nbi) {
          bf16x8 bf = *(const bf16x8*)(tb + h * 8192 + kc * 4096 + boff + nbi * 256);
          acc[0][nbi] =
              __builtin_amdgcn_mfma_f32_32x32x16_bf16(af[0][kc], bf, acc[0][nbi], 0, 0, 0);
          acc[1][nbi] =
              __builtin_amdgcn_mfma_f32_32x32x16_bf16(af[1][kc], bf, acc[1][nbi], 0, 0, 0);
        }
  }
#undef LOAD_ADJ

  // ---- D: lanes l, l+32 hold complementary kh halves of same row ----
  d0 += __shfl_xor(d0, 32);
  d1 += __shfl_xor(d1, 32);
  if (nh == 0 && lane < 32) {
    Dp[(size_t)bj * NN + rbase + l31] = d0;
    Dp[(size_t)bj * NN + rbase + 32 + l31] = d1;
  }

  // ---- U: C/D layout col=lane&31, row=(reg&3)+8*(reg>>2)+4*(lane>>5) ----
  unsigned short* ub = Upb + ((size_t)bj * NN + rbase) * FOUT;
#pragma unroll
  for (int rf = 0; rf < 2; ++rf)
#pragma unroll
    for (int nbi = 0; nbi < 4; ++nbi)
#pragma unroll
      for (int reg = 0; reg < 16; ++reg) {
        const int rr = rf * 32 + (reg & 3) + ((reg >> 2) << 3) + (kh << 2);
        const int cc = nh * 128 + nbi * 32 + l31;
        ub[(size_t)rr * FOUT + cc] = f2bf(acc[rf][nbi][reg]);
      }
}

// ------------- Phase C: combine j-splits, divide, head-mean -------------
__global__ __launch_bounds__(256) void finalize(const unsigned short* __restrict__ Upb,
                                                const float* __restrict__ Dp,
                                                float* __restrict__ out) {
  const int idx = blockIdx.x * 256 + threadIdx.x;  // < 8192*64
  const int i = idx >> 6, c = idx & 63;
  float u = 0.f, d = 0.f;
#pragma unroll
  for (int s = 0; s < JSPLIT; ++s) {
    d += Dp[(size_t)s * NN + i];
    const unsigned short* up = Upb + ((size_t)s * NN + i) * FOUT + c;
#pragma unroll
    for (int g = 0; g < 4; ++g) u += bf2f(up[g * 64]);
  }
  out[idx] = u / (4.f * d);
}

extern "C" void kernel_launch(void* const* d_in, const int* in_sizes, int n_in,
                              void* d_out, int out_size, void* d_ws, size_t ws_size,
                              hipStream_t stream) {
  const float* x = (const float*)d_in[0];
  const int* adj = (const int*)d_in[1];
  const float* W = (const float*)d_in[2];
  const float* a = (const float*)d_in[3];
  char* ws = (char*)d_ws;

  // Layout (42.3 MB total):
  //   Upb  [0, 32 MB)            bf16 U partials (8 splits) -- written by aggr
  //   Wh   [0, 8 MB)             OVERLAPS Upb: dead before aggr runs
  //   Bg   [32 MB, 40 MB)        pre-swizzled bf16 hi/lo B fragments
  //   ssrc/sdst/Dp above 40 MB
  unsigned short* Upb = (unsigned short*)ws;
  float* Wh = (float*)ws;
  unsigned short* Bg = (unsigned short*)(ws + ((size_t)32 << 20));
  float* ssrc = (float*)(ws + ((size_t)40 << 20));
  float* sdst = (float*)(ws + ((size_t)40 << 20) + (32u << 10));
  float* Dp = (float*)(ws + ((size_t)40 << 20) + (64u << 10));
  float* out = (float*)d_out;

  gemm_xw<<<dim3(FOUT / 64, NN / 64), 256, 0, stream>>>(x, W, Wh);
  compute_s<<<NN / 4, 256, 0, stream>>>(Wh, a, ssrc, sdst);
  build_whb<<<(NN / 8) * FOUT / 256, 256, 0, stream>>>(Wh, Bg);
  gat_aggr<<<32 * JSPLIT, 512, 0, stream>>>(adj, ssrc, sdst, Bg, Upb, Dp);
  finalize<<<NN * 64 / 256, 256, 0, stream>>>(Upb, Dp, out);
}

// Round 3
// 126.788 us; speedup vs baseline: 2.0390x; 1.7721x over previous
//
#include <hip/hip_runtime.h>
#include <hip/hip_bf16.h>

#define NN 8192
#define FIN 512
#define FOUT 256
#define FH 64                 // head-mean output cols
#define JSPLIT 16
#define JCHUNK (NN / JSPLIT)  // 512
#define STEPS (JCHUNK / 32)   // 16

typedef float f32x16 __attribute__((ext_vector_type(16)));
typedef short bf16x8 __attribute__((ext_vector_type(8)));
typedef unsigned short us8 __attribute__((ext_vector_type(8)));

static __device__ __forceinline__ unsigned short f2bf(float x) {
  unsigned int u = __builtin_bit_cast(unsigned int, x);
  unsigned int r = (u + 0x7fffu + ((u >> 16) & 1u)) >> 16;  // RNE
  return (unsigned short)r;
}
static __device__ __forceinline__ float bf2f(unsigned short u) {
  unsigned int v = ((unsigned int)u) << 16;
  return __builtin_bit_cast(float, v);
}
static __device__ __forceinline__ float fastexp2(float x) {
  float r;
  asm("v_exp_f32 %0, %1" : "=v"(r) : "v"(x));
  return r;
}

// ---------------- Phase A: Wh = x @ W  (fp32, 64x64 tile) ----------------
__global__ __launch_bounds__(256) void gemm_xw(const float* __restrict__ X,
                                               const float* __restrict__ W,
                                               float* __restrict__ Wh) {
  __shared__ float As[16][68];
  __shared__ float Bs[16][68];
  const int tid = threadIdx.x;
  const int tx = tid & 15, ty = tid >> 4;
  const int m0 = blockIdx.y * 64, n0 = blockIdx.x * 64;
  const int ka = tid & 15, ma = tid >> 4;
  const int nb_ = tid & 63, kb_ = tid >> 6;
  float acc[4][4] = {};
  for (int K0 = 0; K0 < FIN; K0 += 16) {
#pragma unroll
    for (int i = 0; i < 4; ++i)
      As[ka][ma + 16 * i] = X[(size_t)(m0 + ma + 16 * i) * FIN + K0 + ka];
#pragma unroll
    for (int i = 0; i < 4; ++i)
      Bs[kb_ + 4 * i][nb_] = W[(size_t)(K0 + kb_ + 4 * i) * FOUT + n0 + nb_];
    __syncthreads();
#pragma unroll
    for (int k = 0; k < 16; ++k) {
      const float4 av = *(const float4*)&As[k][ty * 4];
      const float4 bv = *(const float4*)&Bs[k][tx * 4];
      const float a4[4] = {av.x, av.y, av.z, av.w};
      const float b4[4] = {bv.x, bv.y, bv.z, bv.w};
#pragma unroll
      for (int i = 0; i < 4; ++i)
#pragma unroll
        for (int j = 0; j < 4; ++j) acc[i][j] += a4[i] * b4[j];
    }
    __syncthreads();
  }
#pragma unroll
  for (int i = 0; i < 4; ++i) {
    float4 v = make_float4(acc[i][0], acc[i][1], acc[i][2], acc[i][3]);
    *(float4*)&Wh[(size_t)(m0 + ty * 4 + i) * FOUT + n0 + tx * 4] = v;
  }
}

// ------- Phase A2: s_src/s_dst (PRE-SCALED by log2(e) for v_exp_f32) -------
__global__ __launch_bounds__(256) void compute_s(const float* __restrict__ Wh,
                                                 const float* __restrict__ a,
                                                 float* __restrict__ ssrc,
                                                 float* __restrict__ sdst) {
  const int wave = threadIdx.x >> 6, lane = threadIdx.x & 63;
  const int row = blockIdx.x * 4 + wave;
  const float4 w = ((const float4*)(Wh + (size_t)row * FOUT))[lane];
  const float4 as = ((const float4*)a)[lane];
  const float4 ad = ((const float4*)(a + FOUT))[lane];
  float vs = w.x * as.x + w.y * as.y + w.z * as.z + w.w * as.w;
  float vd = w.x * ad.x + w.y * ad.y + w.z * ad.z + w.w * ad.w;
#pragma unroll
  for (int off = 32; off; off >>= 1) {
    vs += __shfl_xor(vs, off);
    vd += __shfl_xor(vd, off);
  }
  if (lane == 0) {
    ssrc[row] = vs * 1.44269504f;
    sdst[row] = vd * 1.44269504f;
  }
}

// --- Phase A3: head-mean of Wh -> bf16 hi/lo in 32x32x16 B-frag order ---
// Whm[j][c] = 0.25 * sum_g Wh[j][g*64+c], c<64. Tile per jw (32 j):
// [h(2)][kc(2)][kh(2)][n(64)][e(8)] shorts = 4096 (8KB). Element
// (kc,kh,n,e) = Whm[jw*32 + kc*16 + kh*8 + e][n].
__global__ __launch_bounds__(256) void build_whb(const float* __restrict__ Wh,
                                                 unsigned short* __restrict__ Bg) {
  const int idx = blockIdx.x * 256 + threadIdx.x;  // < 1024*64
  const int jo = idx >> 6, n = idx & 63;           // jo = j>>3
  const int jw = jo >> 2, kc = (jo >> 1) & 1, kh = jo & 1;
  us8 vh, vl;
#pragma unroll
  for (int e = 0; e < 8; ++e) {
    const float* wr = Wh + (size_t)(jo * 8 + e) * FOUT + n;
    float v = 0.25f * (wr[0] + wr[64] + wr[128] + wr[192]);
    unsigned short hi = f2bf(v);
    vh[e] = hi;
    vl[e] = f2bf(v - bf2f(hi));
  }
  const size_t base = (size_t)jw * 4096 + kc * 1024 + kh * 512 + n * 8;
  *(us8*)(Bg + base) = vh;          // h=0 (hi)
  *(us8*)(Bg + base + 2048) = vl;   // h=1 (lo)
}

// ------------- Phase B: fused aggregation, LDS-staged B, 32x32x16 -------------
// grid 1024 = 64 bm x 16 bj (bid&7 = bj&7 -> XCD-pinned-ish; B is tiny anyway).
// Block: 256 thr / 4 waves; wave owns 32 rows x 64 cols. 4 blocks/CU.
#define GLL(G, L)                                                           \
  __builtin_amdgcn_global_load_lds(                                         \
      (const __attribute__((address_space(1))) unsigned int*)(G),           \
      (__attribute__((address_space(3))) unsigned int*)(L), 16, 0, 0)

#define GEN1(V, E, Q, SD)                         \
  {                                               \
    float tt = ss + (SD);                         \
    float lr = fmaxf(tt, 0.2f * tt);              \
    float pe = (Q) ? fastexp2(lr) : 1.0f;         \
    unsigned short hb = f2bf(pe);                 \
    V[E] = (short)hb;                             \
    dacc += bf2f(hb);                             \
  }
#define GEN8(V, QA, QB, SA, SB)                   \
  GEN1(V, 0, (QA).x, (SA).x)                      \
  GEN1(V, 1, (QA).y, (SA).y)                      \
  GEN1(V, 2, (QA).z, (SA).z)                      \
  GEN1(V, 3, (QA).w, (SA).w)                      \
  GEN1(V, 4, (QB).x, (SB).x)                      \
  GEN1(V, 5, (QB).y, (SB).y)                      \
  GEN1(V, 6, (QB).z, (SB).z)                      \
  GEN1(V, 7, (QB).w, (SB).w)

__global__ __launch_bounds__(256, 4) void gat_aggr(
    const int* __restrict__ adj, const float* __restrict__ ssrc_g,
    const float* __restrict__ sdst_g, const unsigned short* __restrict__ Bg,
    float* __restrict__ Up, float* __restrict__ Dp) {
  __shared__ unsigned short lbuf[2][4096];
  const int bid = blockIdx.x;
  const int bj = bid & 15, bm = bid >> 4;
  const int wv = threadIdx.x >> 6, lane = threadIdx.x & 63;
  const int l31 = lane & 31, kh = lane >> 5;
  const int rbase = bm * 128;
  const int myrow = rbase + wv * 32 + l31;
  const int jb = bj * JCHUNK;
  const float ss = ssrc_g[myrow];
  const int* arow = adj + (size_t)myrow * NN + jb + kh * 8;
  const float* sdp = sdst_g + jb + kh * 8;

  f32x16 acc0 = (f32x16)(0.f), acc1 = (f32x16)(0.f);
  float dacc = 0.f;

  // ---- prologue: stage tile 0 + adj regs for t=0 ----
  {
    const unsigned short* gs =
        Bg + (size_t)(bj * STEPS) * 4096 + wv * 512 + lane * 8;
    GLL(gs, &lbuf[0][wv * 512]);
    GLL(gs + 2048, &lbuf[0][2048 + wv * 512]);
  }
  int4 ajA0 = *(const int4*)(arow);
  int4 ajA1 = *(const int4*)(arow + 4);
  int4 ajA2 = *(const int4*)(arow + 16);
  int4 ajA3 = *(const int4*)(arow + 20);
  int4 ajB0, ajB1, ajB2, ajB3;
  __syncthreads();  // vmcnt(0): tile 0 landed

#define STEP(T, CUR, NXT, C0, C1, C2, C3, N0, N1, N2, N3)                   \
  {                                                                         \
    if ((T) + 1 < STEPS) {                                                  \
      const unsigned short* gs = Bg +                                       \
          (size_t)(bj * STEPS + (T) + 1) * 4096 + wv * 512 + lane * 8;      \
      GLL(gs, &lbuf[NXT][wv * 512]);                                        \
      GLL(gs + 2048, &lbuf[NXT][2048 + wv * 512]);                          \
      N0 = *(const int4*)(arow + ((T) + 1) * 32);                           \
      N1 = *(const int4*)(arow + ((T) + 1) * 32 + 4);                       \
      N2 = *(const int4*)(arow + ((T) + 1) * 32 + 16);                      \
      N3 = *(const int4*)(arow + ((T) + 1) * 32 + 20);                      \
    }                                                                       \
    bf16x8 af0, af1;                                                        \
    {                                                                       \
      const float4 sA0 = *(const float4*)(sdp + (T) * 32);                  \
      const float4 sB0 = *(const float4*)(sdp + (T) * 32 + 4);              \
      const float4 sA1 = *(const float4*)(sdp + (T) * 32 + 16);             \
      const float4 sB1 = *(const float4*)(sdp + (T) * 32 + 20);             \
      GEN8(af0, C0, C1, sA0, sB0);                                          \
      GEN8(af1, C2, C3, sA1, sB1);                                          \
    }                                                                       \
    const unsigned short* lb = &lbuf[CUR][kh * 512 + l31 * 8];              \
    bf16x8 b0 = *(const bf16x8*)(lb);         /* kc0 hi n0 */               \
    bf16x8 b1 = *(const bf16x8*)(lb + 256);   /* kc0 hi n1 */               \
    bf16x8 b2 = *(const bf16x8*)(lb + 2048);  /* kc0 lo n0 */               \
    bf16x8 b3 = *(const bf16x8*)(lb + 2304);  /* kc0 lo n1 */               \
    bf16x8 b4 = *(const bf16x8*)(lb + 1024);  /* kc1 hi n0 */               \
    bf16x8 b5 = *(const bf16x8*)(lb + 1280);  /* kc1 hi n1 */               \
    bf16x8 b6 = *(const bf16x8*)(lb + 3072);  /* kc1 lo n0 */               \
    bf16x8 b7 = *(const bf16x8*)(lb + 3328);  /* kc1 lo n1 */               \
    acc0 = __builtin_amdgcn_mfma_f32_32x32x16_bf16(af0, b0, acc0, 0, 0, 0); \
    acc1 = __builtin_amdgcn_mfma_f32_32x32x16_bf16(af0, b1, acc1, 0, 0, 0); \
    acc0 = __builtin_amdgcn_mfma_f32_32x32x16_bf16(af0, b2, acc0, 0, 0, 0); \
    acc1 = __builtin_amdgcn_mfma_f32_32x32x16_bf16(af0, b3, acc1, 0, 0, 0); \
    acc0 = __builtin_amdgcn_mfma_f32_32x32x16_bf16(af1, b4, acc0, 0, 0, 0); \
    acc1 = __builtin_amdgcn_mfma_f32_32x32x16_bf16(af1, b5, acc1, 0, 0, 0); \
    acc0 = __builtin_amdgcn_mfma_f32_32x32x16_bf16(af1, b6, acc0, 0, 0, 0); \
    acc1 = __builtin_amdgcn_mfma_f32_32x32x16_bf16(af1, b7, acc1, 0, 0, 0); \
    __syncthreads();                                                        \
  }

#pragma unroll 1
  for (int it = 0; it < STEPS / 2; ++it) {
    STEP(2 * it, 0, 1, ajA0, ajA1, ajA2, ajA3, ajB0, ajB1, ajB2, ajB3)
    STEP(2 * it + 1, 1, 0, ajB0, ajB1, ajB2, ajB3, ajA0, ajA1, ajA2, ajA3)
  }
#undef STEP

  // ---- D: lanes l, l+32 hold complementary kh halves of same row ----
  dacc += __shfl_xor(dacc, 32);
  if (lane < 32) Dp[(size_t)bj * NN + myrow] = dacc;

  // ---- U: C/D layout col=lane&31, row=(reg&3)+8*(reg>>2)+4*(lane>>5) ----
  float* ub = Up + ((size_t)bj * NN + rbase + wv * 32) * FH;
#pragma unroll
  for (int reg = 0; reg < 16; ++reg) {
    const int rr = (reg & 3) + ((reg >> 2) << 3) + (kh << 2);
    ub[(size_t)rr * FH + l31] = acc0[reg];
    ub[(size_t)rr * FH + 32 + l31] = acc1[reg];
  }
}

// ------------- Phase C: combine j-splits, divide -------------
__global__ __launch_bounds__(256) void finalize(const float* __restrict__ Up,
                                                const float* __restrict__ Dp,
                                                float* __restrict__ out) {
  const int idx = blockIdx.x * 256 + threadIdx.x;  // < 8192*64
  const int i = idx >> 6;
  float u = 0.f, d = 0.f;
#pragma unroll
  for (int s = 0; s < JSPLIT; ++s) {
    d += Dp[(size_t)s * NN + i];
    u += Up[(size_t)s * NN * FH + idx];
  }
  out[idx] = u / d;
}

extern "C" void kernel_launch(void* const* d_in, const int* in_sizes, int n_in,
                              void* d_out, int out_size, void* d_ws, size_t ws_size,
                              hipStream_t stream) {
  const float* x = (const float*)d_in[0];
  const int* adj = (const int*)d_in[1];
  const float* W = (const float*)d_in[2];
  const float* a = (const float*)d_in[3];
  char* ws = (char*)d_ws;

  // ws layout (~34.6 MB):
  //   Up  [0, 32 MB)   f32 U partials (16 splits x 8192 x 64)
  //   Wh  [0, 8 MB)    OVERLAPS Up: dead before gat_aggr runs
  //   Bg  [32, 34 MB)  pre-swizzled bf16 hi/lo head-mean B fragments
  //   ssrc/sdst/Dp above 34 MB
  float* Up = (float*)ws;
  float* Wh = (float*)ws;
  unsigned short* Bg = (unsigned short*)(ws + ((size_t)32 << 20));
  float* ssrc = (float*)(ws + ((size_t)34 << 20));
  float* sdst = (float*)(ws + ((size_t)34 << 20) + (32u << 10));
  float* Dp = (float*)(ws + ((size_t)34 << 20) + (64u << 10));
  float* out = (float*)d_out;

  gemm_xw<<<dim3(FOUT / 64, NN / 64), 256, 0, stream>>>(x, W, Wh);
  compute_s<<<NN / 4, 256, 0, stream>>>(Wh, a, ssrc, sdst);
  build_whb<<<(NN / 8) * FH / 256, 256, 0, stream>>>(Wh, Bg);
  gat_aggr<<<64 * JSPLIT, 256, 0, stream>>>(adj, ssrc, sdst, Bg, Up, Dp);
  finalize<<<NN * FH / 256, 256, 0, stream>>>(Up, Dp, out);
}